// Round 7
// baseline (884.463 us; speedup 1.0000x reference)
//
#include <hip/hip_runtime.h>

namespace {
constexpr int B_ = 8, H_ = 16, CI_ = 16, O_ = 16, P_ = 14;
constexpr int P2_ = P_ * P_;    // 196
constexpr int NB_ = B_ * P2_;   // 1568 patches
constexpr int K2CI_ = 144;
constexpr int NV_ = 2304;       // z per patch, layout [k][o]
constexpr int NP_ = 4;          // patches (batch-dim) per block
constexpr float EPS_ = 1e-9f;
constexpr float LOG2PI_ = 1.8378770664093453f;

using f2 = __attribute__((ext_vector_type(2))) float;

__device__ __forceinline__ float cnt1(int h) {
  int lo = (h - (P_ - 1)) > 0 ? (h - (P_ - 1)) : 0;
  int hi = h < 2 ? h : 2;
  return (float)(hi - lo + 1);
}

// Fused prologue: blocks [0,2048) transpose pose (4x4 per cell -> [q][p]);
// blocks [2048,2192) transpose w -> wt[k][o][r][q].
__global__ __launch_bounds__(256) void transpose_all(const float* __restrict__ pose,
                                                     float* __restrict__ pose_t,
                                                     const float* __restrict__ w,
                                                     float* __restrict__ wt) {
  if (blockIdx.x < 2048) {
    const int i = blockIdx.x * 256 + threadIdx.x;  // 0..524287
    const int cell = i >> 4, idx = i & 15;
    const int p = idx >> 2, q = idx & 3;
    pose_t[(cell << 4) + (q << 2) + p] = pose[i];
  } else {
    const int i = (blockIdx.x - 2048) * 256 + threadIdx.x;  // 0..36863
    const int ko = i >> 4, q = (i >> 2) & 3, r = i & 3;
    wt[(ko << 4) + (r << 2) + q] = w[i];
  }
}

// One BLOCK (256 thr, 4 waves) per 4 PATCHES (b0..b0+3, same pi,pj).
// R5/R6 showed launch time tracks per-patch wt traffic (147 KB/patch/pass
// through L2) — batching 4 b-patches per block reuses each w4 register load
// 4x, cutting wt stream and amortizing its L2 latency over 4x arithmetic.
// Wave wv owns ci in {4wv..4wv+3} across all 9 kk (36 idx); lane = o*4 + r.
// Pose via block-uniform scalar loads from pose_t (single SGPR base,
// compile-time immediates incl. the u*256KB batch stride).
// MODE 0: rr uniform -> z. MODE 1: rr softmax -> z. MODE 2: rr softmax -> out.
template <int MODE>
__global__ __launch_bounds__(256, 4) void caps_main(
    const float* __restrict__ pose_t, const float* __restrict__ act,
    const float* __restrict__ wt, const float* __restrict__ beta_a,
    const float* __restrict__ beta_v, const float* __restrict__ zin,
    const float* __restrict__ gmax, const float* __restrict__ gden,
    float* __restrict__ zout, float* __restrict__ out) {
  __shared__ float rr_s[NP_ * ((MODE == 0) ? K2CI_ : NV_)];  // [u][...]
  __shared__ f2 partv[4][256];                               // pm01, pm23, pv01, pv23
  __shared__ float partr[256];                               // prr
  __shared__ f2 sfin[4][64];
  __shared__ float sfr[64];
  __shared__ float gm_s[(MODE == 0) ? 1 : NP_ * K2CI_];
  __shared__ float ad_s[(MODE == 0) ? 1 : NP_ * K2CI_];

  const int tid = threadIdx.x;
  const int wv = __builtin_amdgcn_readfirstlane(tid >> 6);
  const int l = tid & 63;
  const int o = l >> 2, r = l & 3;
  const int tile = blockIdx.x;        // 0..391
  const int bt = tile / P2_;          // 0..1
  const int p2 = tile - bt * P2_;
  const int b0 = bt * NP_;
  const int pi = p2 / P_;
  const int pj = p2 - pi * P_;
  const float inv_temp = (MODE == 0) ? 0.0005f : (MODE == 1) ? 0.000975f : 0.00142625f;

  // ---- prologue: stage rr (or gmax/act-den) for all NP_ patches ----
  if (tid < K2CI_) {
    const int ci = tid & 15, kk = tid >> 4;
    const int ki = (kk >= 6) ? 2 : (kk >= 3) ? 1 : 0, kj = kk - 3 * ki;
    const int cell = (pi + ki) * H_ + (pj + kj);
    const float inv_cnt = 1.0f / (16.0f * cnt1(pi + ki) * cnt1(pj + kj));
#pragma unroll
    for (int u = 0; u < NP_; ++u) {
      const int cidx = ((b0 + u) * H_ * H_ + cell) * CI_ + ci;
      if (MODE == 0) {
        rr_s[u * K2CI_ + tid] = act[cidx] * inv_cnt;
      } else {
        gm_s[u * K2CI_ + tid] = gmax[cidx];
        ad_s[u * K2CI_ + tid] = act[cidx] / (gden[cidx] + EPS_);
      }
    }
  }
  if (MODE != 0) {
    __syncthreads();
    for (int i4 = tid; i4 < NP_ * NV_ / 4; i4 += 256) {
      const int u = i4 / (NV_ / 4);
      const int j4 = i4 - u * (NV_ / 4);
      const int pid = (b0 + u) * P2_ + p2;
      const float4 z4 = ((const float4*)(zin + (size_t)pid * NV_))[j4];
      const int k = j4 >> 2;
      const float gmk = gm_s[u * K2CI_ + k], adk = ad_s[u * K2CI_ + k];
      float4 r4;
      r4.x = __expf(z4.x - gmk) * adk;
      r4.y = __expf(z4.y - gmk) * adk;
      r4.z = __expf(z4.z - gmk) * adk;
      r4.w = __expf(z4.w - gmk) * adk;
      ((float4*)rr_s)[i4] = r4;  // layout [u][NV_]
    }
  }
  __syncthreads();

  const float bvo = 16.0f * beta_v[o];
  const float bao = beta_a[o];

  // block-uniform base; batch stride 65536 floats (256 KB) fits s_load imm
  const float* pose_b = pose_t + ((size_t)((b0 * H_ + pi) * H_ + pj) << 8);
  const float* wt_l = wt + (l << 2);
  const int ci0 = wv * 4;

  // idx in [0,36): kk = idx>>2, ci = ci0 + (idx&3)
#define WT_OFF(idx) ((((idx) >> 2) << 12) + ((ci0 + ((idx)&3)) << 8))
#define PB_OFF(idx) (((((idx) >> 2) / 3) << 12) + ((((idx) >> 2) % 3) << 8) + ((ci0 + ((idx)&3)) << 4))

  // ---- pass 1: packed fused mean+var partials; w4 shared across NP_ patches ----
  f2 pm01[NP_], pm23[NP_], pv01[NP_], pv23[NP_];
  float prr[NP_];
#pragma unroll
  for (int u = 0; u < NP_; ++u) {
    pm01[u] = (f2){0.f, 0.f}; pm23[u] = (f2){0.f, 0.f};
    pv01[u] = (f2){0.f, 0.f}; pv23[u] = (f2){0.f, 0.f};
    prr[u] = 0.f;
  }
  {
    float4 wbuf0 = *(const float4*)(wt_l + WT_OFF(0));
    float4 wbuf1 = *(const float4*)(wt_l + WT_OFF(1));
#pragma unroll
    for (int idx = 0; idx < 36; ++idx) {
      const float4 w4 = (idx & 1) ? wbuf1 : wbuf0;
      if (idx < 34) {
        if (idx & 1)
          wbuf1 = *(const float4*)(wt_l + WT_OFF(idx + 2));
        else
          wbuf0 = *(const float4*)(wt_l + WT_OFF(idx + 2));
      }
      const int k = ((idx >> 2) << 4) + ci0 + (idx & 3);
#pragma unroll
      for (int u = 0; u < NP_; ++u) {
        const float* pb = pose_b + (u << 16) + PB_OFF(idx);
        const float4 P0 = *(const float4*)(pb);
        const float4 P1 = *(const float4*)(pb + 4);
        const float4 P2 = *(const float4*)(pb + 8);
        const float4 P3 = *(const float4*)(pb + 12);
        f2 v01 = (f2){P0.x, P0.y} * w4.x;
        f2 v23 = (f2){P0.z, P0.w} * w4.x;
        v01 = __builtin_elementwise_fma((f2){P1.x, P1.y}, (f2){w4.y, w4.y}, v01);
        v23 = __builtin_elementwise_fma((f2){P1.z, P1.w}, (f2){w4.y, w4.y}, v23);
        v01 = __builtin_elementwise_fma((f2){P2.x, P2.y}, (f2){w4.z, w4.z}, v01);
        v23 = __builtin_elementwise_fma((f2){P2.z, P2.w}, (f2){w4.z, w4.z}, v23);
        v01 = __builtin_elementwise_fma((f2){P3.x, P3.y}, (f2){w4.w, w4.w}, v01);
        v23 = __builtin_elementwise_fma((f2){P3.z, P3.w}, (f2){w4.w, w4.w}, v23);
        const float rrk = (MODE == 0) ? rr_s[u * K2CI_ + k] : rr_s[u * NV_ + (k << 4) + o];
        prr[u] += rrk;
        const f2 rr2 = {rrk, rrk};
        const f2 a01 = rr2 * v01, a23 = rr2 * v23;
        pm01[u] += a01;
        pm23[u] += a23;
        pv01[u] = __builtin_elementwise_fma(a01, v01, pv01[u]);
        pv23[u] = __builtin_elementwise_fma(a23, v23, pv23[u]);
      }
    }
  }

  // ---- per-patch cross-wave combine + routing scalars ----
  f2 m01r[NP_], m23r[NP_], iv01r[NP_], iv23r[NP_];
  float Czr[NP_];
#pragma unroll
  for (int u = 0; u < NP_; ++u) {
    partv[0][tid] = pm01[u]; partv[1][tid] = pm23[u];
    partv[2][tid] = pv01[u]; partv[3][tid] = pv23[u];
    partr[tid] = prr[u];
    __syncthreads();
    {
      const int st = tid >> 6, li = tid & 63;
      f2 acc = partv[st][li];
#pragma unroll
      for (int wvi = 1; wvi < 4; ++wvi) acc += partv[st][wvi * 64 + li];
      sfin[st][li] = acc;
    }
    if (tid < 64) {
      float acc = partr[tid];
#pragma unroll
      for (int wvi = 1; wvi < 4; ++wvi) acc += partr[wvi * 64 + tid];
      sfr[tid] = acc;
    }
    __syncthreads();
    const f2 S01 = sfin[0][l], S23 = sfin[1][l];
    const f2 V01 = sfin[2][l], V23 = sfin[3][l];
    const float rsum = sfr[l] + EPS_;
    const float irs = 1.0f / rsum;
    const f2 irs2 = {irs, irs};
    const f2 m01 = S01 * irs2, m23 = S23 * irs2;
    const f2 zero2 = {0.f, 0.f}, eps2 = {EPS_, EPS_};
    const f2 va01 = __builtin_elementwise_max(V01 * irs2 - m01 * m01, zero2) + eps2;
    const f2 va23 = __builtin_elementwise_max(V23 * irs2 - m23 * m23, zero2) + eps2;
    float slv = __logf(va01.x) + __logf(va01.y) + __logf(va23.x) + __logf(va23.y);
    slv += __shfl_xor(slv, 1);
    slv += __shfl_xor(slv, 2);
    const float cost = (bvo + 0.5f * slv) * rsum;
    const float aj = 1.0f / (1.0f + __expf(-inv_temp * (bao - cost)));
    if (MODE == 2) {
      if (wv == 0) {
        const int pid = (b0 + u) * P2_ + p2;
        float* ob = out + ((size_t)(pid * 16 + o) << 4) + r;
        ob[0] = m01.x; ob[4] = m01.y; ob[8] = m23.x; ob[12] = m23.y;
        if (r == 0) out[(size_t)B_ * P2_ * O_ * 16 + pid * 16 + o] = aj;
      }
    } else {
      m01r[u] = m01; m23r[u] = m23;
      iv01r[u] = (f2){1.0f / va01.x, 1.0f / va01.y};
      iv23r[u] = (f2){1.0f / va23.x, 1.0f / va23.y};
      Czr[u] = __logf(aj + EPS_) - 0.5f * (slv + 16.0f * LOG2PI_);
    }
  }
  if (MODE == 2) return;

  // ---- pass 2: recompute votes (w4 shared across patches), write z[k][o] ----
  {
    float4 wbuf0 = *(const float4*)(wt_l + WT_OFF(0));
    float4 wbuf1 = *(const float4*)(wt_l + WT_OFF(1));
#pragma unroll
    for (int idx = 0; idx < 36; ++idx) {
      const float4 w4 = (idx & 1) ? wbuf1 : wbuf0;
      if (idx < 34) {
        if (idx & 1)
          wbuf1 = *(const float4*)(wt_l + WT_OFF(idx + 2));
        else
          wbuf0 = *(const float4*)(wt_l + WT_OFF(idx + 2));
      }
      const int k = ((idx >> 2) << 4) + ci0 + (idx & 3);
#pragma unroll
      for (int u = 0; u < NP_; ++u) {
        const float* pb = pose_b + (u << 16) + PB_OFF(idx);
        const float4 P0 = *(const float4*)(pb);
        const float4 P1 = *(const float4*)(pb + 4);
        const float4 P2 = *(const float4*)(pb + 8);
        const float4 P3 = *(const float4*)(pb + 12);
        f2 v01 = (f2){P0.x, P0.y} * w4.x;
        f2 v23 = (f2){P0.z, P0.w} * w4.x;
        v01 = __builtin_elementwise_fma((f2){P1.x, P1.y}, (f2){w4.y, w4.y}, v01);
        v23 = __builtin_elementwise_fma((f2){P1.z, P1.w}, (f2){w4.y, w4.y}, v23);
        v01 = __builtin_elementwise_fma((f2){P2.x, P2.y}, (f2){w4.z, w4.z}, v01);
        v23 = __builtin_elementwise_fma((f2){P2.z, P2.w}, (f2){w4.z, w4.z}, v23);
        v01 = __builtin_elementwise_fma((f2){P3.x, P3.y}, (f2){w4.w, w4.w}, v01);
        v23 = __builtin_elementwise_fma((f2){P3.z, P3.w}, (f2){w4.w, w4.w}, v23);
        const f2 d01 = v01 - m01r[u], d23 = v23 - m23r[u];
        const f2 q2 =
            __builtin_elementwise_fma(d01 * d01, iv01r[u], (d23 * d23) * iv23r[u]);
        float q = q2.x + q2.y;
        q += __shfl_xor(q, 1);
        q += __shfl_xor(q, 2);
        if (r == 0) {
          const int pid = (b0 + u) * P2_ + p2;
          zout[(size_t)pid * NV_ + (k << 4) + o] = Czr[u] - 0.5f * q;
        }
      }
    }
  }
#undef WT_OFF
#undef PB_OFF
}

// 4 threads per segment (b,h,w,ci); z cached in registers between max and sum.
__global__ __launch_bounds__(256) void seg_reduce(const float* __restrict__ z,
                                                  float* __restrict__ gmax,
                                                  float* __restrict__ gden) {
  const int tid = blockIdx.x * 256 + threadIdx.x;  // 0..131071
  const int part = tid & 3, ci = (tid >> 2) & 15, w2 = (tid >> 6) & 15;
  const int h = (tid >> 10) & 15, b = tid >> 14;
  float4 v[9];
  float m = -3.0e38f;
#pragma unroll
  for (int s = 0; s < 9; ++s) {
    const int ki = (s >= 6) ? 2 : (s >= 3) ? 1 : 0, kj = s - 3 * ki;
    const int pi = h - ki, pj = w2 - kj;
    if ((unsigned)pi < (unsigned)P_ && (unsigned)pj < (unsigned)P_) {
      v[s] = *(const float4*)(z + (size_t)(b * P2_ + pi * P_ + pj) * NV_ + s * 256 +
                              ci * 16 + part * 4);
    } else {
      v[s] = make_float4(-3.0e38f, -3.0e38f, -3.0e38f, -3.0e38f);
    }
    m = fmaxf(m, fmaxf(fmaxf(v[s].x, v[s].y), fmaxf(v[s].z, v[s].w)));
  }
  m = fmaxf(m, __shfl_xor(m, 1));
  m = fmaxf(m, __shfl_xor(m, 2));
  float s_ = 0.f;
#pragma unroll
  for (int s = 0; s < 9; ++s) {
    s_ += __expf(v[s].x - m) + __expf(v[s].y - m) + __expf(v[s].z - m) + __expf(v[s].w - m);
  }
  s_ += __shfl_xor(s_, 1);
  s_ += __shfl_xor(s_, 2);
  if (part == 0) {
    gmax[tid >> 2] = m;
    gden[tid >> 2] = s_;
  }
}
}  // namespace

extern "C" void kernel_launch(void* const* d_in, const int* in_sizes, int n_in,
                              void* d_out, int out_size, void* d_ws, size_t ws_size,
                              hipStream_t stream) {
  const float* pose = (const float*)d_in[0];
  const float* act = (const float*)d_in[1];
  const float* w = (const float*)d_in[2];
  const float* ba = (const float*)d_in[3];
  const float* bv = (const float*)d_in[4];
  float* out = (float*)d_out;

  float* z = (float*)d_ws;                  // 3,612,672 floats, layout [pid][k][o]
  float* gm = z + (size_t)NB_ * NV_;        // 32,768
  float* gd = gm + B_ * H_ * H_ * CI_;      // 32,768
  float* wt = gd + B_ * H_ * H_ * CI_;      // 36,864
  float* pt = wt + 36864;                   // 524,288 (pose transposed)

  const int NT = (B_ / NP_) * P2_;  // 392 blocks, 4 patches each
  transpose_all<<<2192, 256, 0, stream>>>(pose, pt, w, wt);
  caps_main<0><<<NT, 256, 0, stream>>>(pt, act, wt, ba, bv, z, gm, gd, z, out);
  seg_reduce<<<512, 256, 0, stream>>>(z, gm, gd);
  caps_main<1><<<NT, 256, 0, stream>>>(pt, act, wt, ba, bv, z, gm, gd, z, out);
  seg_reduce<<<512, 256, 0, stream>>>(z, gm, gd);
  caps_main<2><<<NT, 256, 0, stream>>>(pt, act, wt, ba, bv, z, gm, gd, z, out);
}

// Round 8
// 168.280 us; speedup vs baseline: 5.2559x; 5.2559x over previous
//
#include <hip/hip_runtime.h>

namespace {
constexpr int B_ = 8, H_ = 16, CI_ = 16, O_ = 16, P_ = 14;
constexpr int P2_ = P_ * P_;    // 196
constexpr int NB_ = B_ * P2_;   // 1568 patches
constexpr int K2CI_ = 144;
constexpr int NV_ = 2304;       // z per patch, layout [k][o]
constexpr float EPS_ = 1e-9f;
constexpr float LOG2PI_ = 1.8378770664093453f;

using f2 = __attribute__((ext_vector_type(2))) float;

__device__ __forceinline__ float cnt1(int h) {
  int lo = (h - (P_ - 1)) > 0 ? (h - (P_ - 1)) : 0;
  int hi = h < 2 ? h : 2;
  return (float)(hi - lo + 1);
}

// Fused prologue: blocks [0,2048) transpose pose (4x4 per cell -> [q][p]);
// blocks [2048,2192) transpose w -> wt[k][o][r][q].
__global__ __launch_bounds__(256) void transpose_all(const float* __restrict__ pose,
                                                     float* __restrict__ pose_t,
                                                     const float* __restrict__ w,
                                                     float* __restrict__ wt) {
  if (blockIdx.x < 2048) {
    const int i = blockIdx.x * 256 + threadIdx.x;  // 0..524287
    const int cell = i >> 4, idx = i & 15;
    const int p = idx >> 2, q = idx & 3;
    pose_t[(cell << 4) + (q << 2) + p] = pose[i];
  } else {
    const int i = (blockIdx.x - 2048) * 256 + threadIdx.x;  // 0..36863
    const int ko = i >> 4, q = (i >> 2) & 3, r = i & 3;
    wt[(ko << 4) + (r << 2) + q] = w[i];
  }
}

// One BLOCK (256 thr, 4 waves) per patch — sized for SINGLE-ROUND FULL-GRID
// RESIDENCY: 8 blocks/CU x 256 CU = 2048 slots >= 1568 blocks. R6 counters
// (Occ 33%, VALUBusy 33%, dur invariant ~51us) fit a 2-round schedule whose
// 2nd round runs 32 blocks on an empty GPU; this version eliminates it.
// Requirements met: VGPR<=64 via __launch_bounds__(256,8); LDS 18432B (<=20480)
// via liveness overlay: rr_s (dead after pass1) shares with sfin/sfr;
// gm_s/ad_s (dead after prologue) share with partv/partr.
// Wave wv owns ci in {4wv..4wv+3} across all 9 kk (36 idx); lane = o*4 + r.
// Pose via block-uniform scalar loads from pose_t (SMEM path). wt depth-4
// register prefetch (covers ~200cyc L2 latency at ~60 VALU-cyc/iter).
// MODE 0: rr uniform -> z. MODE 1: rr softmax -> z. MODE 2: rr softmax -> out.
template <int MODE>
__global__ __launch_bounds__(256, 8) void caps_main(
    const float* __restrict__ pose_t, const float* __restrict__ act,
    const float* __restrict__ wt, const float* __restrict__ beta_a,
    const float* __restrict__ beta_v, const float* __restrict__ zin,
    const float* __restrict__ gmax, const float* __restrict__ gden,
    float* __restrict__ zout, float* __restrict__ out) {
  // ---- LDS overlay (18432 B) ----
  // region1 [0,9216):     rr_s (prologue..pass1)  |  sfin+sfr (combine..end)
  // region2 [9216,18432): gm_s+ad_s (prologue)    |  partv+partr (post-pass1..combine)
  __shared__ __align__(16) char smem[18432];
  float* rr_s = (float*)smem;                         // 9216 B (MODE0: 576 B)
  f2(*partv)[256] = (f2(*)[256])(smem + 9216);        // 8192 B
  float* partr = (float*)(smem + 9216 + 8192);        // 1024 B
  f2(*sfin)[64] = (f2(*)[64])smem;                    // 2048 B (aliases rr_s)
  float* sfr = (float*)(smem + 2048);                 // 256 B
  float* gm_s = (float*)(smem + 9216);                // 576 B (aliases partv)
  float* ad_s = (float*)(smem + 9216 + 576);          // 576 B

  const int tid = threadIdx.x;
  const int wv = __builtin_amdgcn_readfirstlane(tid >> 6);
  const int l = tid & 63;
  const int o = l >> 2, r = l & 3;
  const int pid = blockIdx.x;
  const int b = pid / P2_;
  const int p2 = pid - b * P2_;
  const int pi = p2 / P_;
  const int pj = p2 - pi * P_;
  const float inv_temp = (MODE == 0) ? 0.0005f : (MODE == 1) ? 0.000975f : 0.00142625f;

  // ---- prologue: stage rr (or gmax/act-den) into LDS ----
  if (tid < K2CI_) {
    const int ci = tid & 15, kk = tid >> 4;
    const int ki = (kk >= 6) ? 2 : (kk >= 3) ? 1 : 0, kj = kk - 3 * ki;
    const int cidx = ((b * H_ + pi + ki) * H_ + pj + kj) * CI_ + ci;
    if (MODE == 0) {
      rr_s[tid] = act[cidx] / (16.0f * cnt1(pi + ki) * cnt1(pj + kj));
    } else {
      gm_s[tid] = gmax[cidx];
      ad_s[tid] = act[cidx] / (gden[cidx] + EPS_);
    }
  }
  if (MODE != 0) {
    __syncthreads();
    for (int i4 = tid; i4 < NV_ / 4; i4 += 256) {
      const float4 z4 = ((const float4*)(zin + (size_t)pid * NV_))[i4];
      const int k = i4 >> 2;
      const float gmk = gm_s[k], adk = ad_s[k];
      float4 r4;
      r4.x = __expf(z4.x - gmk) * adk;
      r4.y = __expf(z4.y - gmk) * adk;
      r4.z = __expf(z4.z - gmk) * adk;
      r4.w = __expf(z4.w - gmk) * adk;
      ((float4*)rr_s)[i4] = r4;
    }
  }
  __syncthreads();

  const float bvo = 16.0f * beta_v[o];
  const float bao = beta_a[o];

  // block-uniform base; per-idx offsets compile-time after unroll -> s_load path
  const float* pose_b = pose_t + ((size_t)((b * H_ + pi) * H_ + pj) << 8);
  const float* wt_l = wt + (l << 2);
  const int ci0 = wv * 4;

  // idx in [0,36): kk = idx>>2, ci = ci0 + (idx&3)
  // wt float-offset:     kk*4096 + ci*256
  // pose_t float-offset: (kk/3)*4096 + (kk%3)*256 + ci*16
#define WT_OFF(idx) ((((idx) >> 2) << 12) + ((ci0 + ((idx)&3)) << 8))
#define PB_OFF(idx) (((((idx) >> 2) / 3) << 12) + ((((idx) >> 2) % 3) << 8) + ((ci0 + ((idx)&3)) << 4))

  // ---- pass 1: packed fused mean+var partials; depth-4 wt prefetch ----
  float prr = 0.f;
  f2 pm01 = {0.f, 0.f}, pm23 = {0.f, 0.f}, pv01 = {0.f, 0.f}, pv23 = {0.f, 0.f};
  {
    float4 wbuf[4];
#pragma unroll
    for (int j = 0; j < 4; ++j) wbuf[j] = *(const float4*)(wt_l + WT_OFF(j));
#pragma unroll
    for (int idx = 0; idx < 36; ++idx) {
      const float4 w4 = wbuf[idx & 3];
      if (idx < 32) wbuf[idx & 3] = *(const float4*)(wt_l + WT_OFF(idx + 4));
      const float* pb = pose_b + PB_OFF(idx);
      const float4 P0 = *(const float4*)(pb);
      const float4 P1 = *(const float4*)(pb + 4);
      const float4 P2 = *(const float4*)(pb + 8);
      const float4 P3 = *(const float4*)(pb + 12);
      f2 v01 = (f2){P0.x, P0.y} * w4.x;
      f2 v23 = (f2){P0.z, P0.w} * w4.x;
      v01 = __builtin_elementwise_fma((f2){P1.x, P1.y}, (f2){w4.y, w4.y}, v01);
      v23 = __builtin_elementwise_fma((f2){P1.z, P1.w}, (f2){w4.y, w4.y}, v23);
      v01 = __builtin_elementwise_fma((f2){P2.x, P2.y}, (f2){w4.z, w4.z}, v01);
      v23 = __builtin_elementwise_fma((f2){P2.z, P2.w}, (f2){w4.z, w4.z}, v23);
      v01 = __builtin_elementwise_fma((f2){P3.x, P3.y}, (f2){w4.w, w4.w}, v01);
      v23 = __builtin_elementwise_fma((f2){P3.z, P3.w}, (f2){w4.w, w4.w}, v23);
      const int k = ((idx >> 2) << 4) + ci0 + (idx & 3);
      const float rrk = (MODE == 0) ? rr_s[k] : rr_s[(k << 4) + o];
      prr += rrk;
      const f2 rr2 = {rrk, rrk};
      const f2 a01 = rr2 * v01, a23 = rr2 * v23;
      pm01 += a01;
      pm23 += a23;
      pv01 = __builtin_elementwise_fma(a01, v01, pv01);
      pv23 = __builtin_elementwise_fma(a23, v23, pv23);
    }
  }
  // ---- cross-wave combine (4 waves); partv aliases dead gm/ad, sfin aliases dead rr_s ----
  __syncthreads();  // ensure all rr_s reads complete before region reuse
  partv[0][tid] = pm01; partv[1][tid] = pm23;
  partv[2][tid] = pv01; partv[3][tid] = pv23;
  partr[tid] = prr;
  __syncthreads();
  {
    const int st = tid >> 6, li = tid & 63;
    f2 acc = partv[st][li];
#pragma unroll
    for (int wvi = 1; wvi < 4; ++wvi) acc += partv[st][wvi * 64 + li];
    sfin[st][li] = acc;
  }
  if (tid < 64) {
    float acc = partr[tid];
#pragma unroll
    for (int wvi = 1; wvi < 4; ++wvi) acc += partr[wvi * 64 + tid];
    sfr[tid] = acc;
  }
  __syncthreads();
  const f2 S01 = sfin[0][l], S23 = sfin[1][l];
  const f2 V01 = sfin[2][l], V23 = sfin[3][l];
  const float rsum = sfr[l] + EPS_;
  const float irs = 1.0f / rsum;
  const f2 irs2 = {irs, irs};
  const f2 m01 = S01 * irs2, m23 = S23 * irs2;
  const f2 zero2 = {0.f, 0.f}, eps2 = {EPS_, EPS_};
  const f2 va01 = __builtin_elementwise_max(V01 * irs2 - m01 * m01, zero2) + eps2;
  const f2 va23 = __builtin_elementwise_max(V23 * irs2 - m23 * m23, zero2) + eps2;
  float slv = __logf(va01.x) + __logf(va01.y) + __logf(va23.x) + __logf(va23.y);
  slv += __shfl_xor(slv, 1);
  slv += __shfl_xor(slv, 2);
  const float cost = (bvo + 0.5f * slv) * rsum;
  const float aj = 1.0f / (1.0f + __expf(-inv_temp * (bao - cost)));

  if (MODE == 2) {
    if (wv == 0) {
      float* ob = out + ((size_t)(pid * 16 + o) << 4) + r;
      ob[0] = m01.x; ob[4] = m01.y; ob[8] = m23.x; ob[12] = m23.y;
      if (r == 0) out[(size_t)B_ * P2_ * O_ * 16 + pid * 16 + o] = aj;
    }
    return;
  }

  // ---- pass 2: recompute votes (depth-4 wt prefetch), write z[k][o] ----
  const f2 iv01 = {1.0f / va01.x, 1.0f / va01.y};
  const f2 iv23 = {1.0f / va23.x, 1.0f / va23.y};
  const float Cz = __logf(aj + EPS_) - 0.5f * (slv + 16.0f * LOG2PI_);
  float* zo = zout + (size_t)pid * NV_ + o;
  {
    float4 wbuf[4];
#pragma unroll
    for (int j = 0; j < 4; ++j) wbuf[j] = *(const float4*)(wt_l + WT_OFF(j));
#pragma unroll
    for (int idx = 0; idx < 36; ++idx) {
      const float4 w4 = wbuf[idx & 3];
      if (idx < 32) wbuf[idx & 3] = *(const float4*)(wt_l + WT_OFF(idx + 4));
      const float* pb = pose_b + PB_OFF(idx);
      const float4 P0 = *(const float4*)(pb);
      const float4 P1 = *(const float4*)(pb + 4);
      const float4 P2 = *(const float4*)(pb + 8);
      const float4 P3 = *(const float4*)(pb + 12);
      f2 v01 = (f2){P0.x, P0.y} * w4.x;
      f2 v23 = (f2){P0.z, P0.w} * w4.x;
      v01 = __builtin_elementwise_fma((f2){P1.x, P1.y}, (f2){w4.y, w4.y}, v01);
      v23 = __builtin_elementwise_fma((f2){P1.z, P1.w}, (f2){w4.y, w4.y}, v23);
      v01 = __builtin_elementwise_fma((f2){P2.x, P2.y}, (f2){w4.z, w4.z}, v01);
      v23 = __builtin_elementwise_fma((f2){P2.z, P2.w}, (f2){w4.z, w4.z}, v23);
      v01 = __builtin_elementwise_fma((f2){P3.x, P3.y}, (f2){w4.w, w4.w}, v01);
      v23 = __builtin_elementwise_fma((f2){P3.z, P3.w}, (f2){w4.w, w4.w}, v23);
      const f2 d01 = v01 - m01, d23 = v23 - m23;
      const f2 q2 = __builtin_elementwise_fma(d01 * d01, iv01, (d23 * d23) * iv23);
      float q = q2.x + q2.y;
      q += __shfl_xor(q, 1);
      q += __shfl_xor(q, 2);
      const int k = ((idx >> 2) << 4) + ci0 + (idx & 3);
      if (r == 0) zo[k << 4] = Cz - 0.5f * q;  // 16 lanes -> one 64B line
    }
  }
#undef WT_OFF
#undef PB_OFF
}

// 4 threads per segment (b,h,w,ci); z cached in registers between max and sum.
__global__ __launch_bounds__(256) void seg_reduce(const float* __restrict__ z,
                                                  float* __restrict__ gmax,
                                                  float* __restrict__ gden) {
  const int tid = blockIdx.x * 256 + threadIdx.x;  // 0..131071
  const int part = tid & 3, ci = (tid >> 2) & 15, w2 = (tid >> 6) & 15;
  const int h = (tid >> 10) & 15, b = tid >> 14;
  float4 v[9];
  float m = -3.0e38f;
#pragma unroll
  for (int s = 0; s < 9; ++s) {
    const int ki = (s >= 6) ? 2 : (s >= 3) ? 1 : 0, kj = s - 3 * ki;
    const int pi = h - ki, pj = w2 - kj;
    if ((unsigned)pi < (unsigned)P_ && (unsigned)pj < (unsigned)P_) {
      v[s] = *(const float4*)(z + (size_t)(b * P2_ + pi * P_ + pj) * NV_ + s * 256 +
                              ci * 16 + part * 4);
    } else {
      v[s] = make_float4(-3.0e38f, -3.0e38f, -3.0e38f, -3.0e38f);
    }
    m = fmaxf(m, fmaxf(fmaxf(v[s].x, v[s].y), fmaxf(v[s].z, v[s].w)));
  }
  m = fmaxf(m, __shfl_xor(m, 1));
  m = fmaxf(m, __shfl_xor(m, 2));
  float s_ = 0.f;
#pragma unroll
  for (int s = 0; s < 9; ++s) {
    s_ += __expf(v[s].x - m) + __expf(v[s].y - m) + __expf(v[s].z - m) + __expf(v[s].w - m);
  }
  s_ += __shfl_xor(s_, 1);
  s_ += __shfl_xor(s_, 2);
  if (part == 0) {
    gmax[tid >> 2] = m;
    gden[tid >> 2] = s_;
  }
}
}  // namespace

extern "C" void kernel_launch(void* const* d_in, const int* in_sizes, int n_in,
                              void* d_out, int out_size, void* d_ws, size_t ws_size,
                              hipStream_t stream) {
  const float* pose = (const float*)d_in[0];
  const float* act = (const float*)d_in[1];
  const float* w = (const float*)d_in[2];
  const float* ba = (const float*)d_in[3];
  const float* bv = (const float*)d_in[4];
  float* out = (float*)d_out;

  float* z = (float*)d_ws;                  // 3,612,672 floats, layout [pid][k][o]
  float* gm = z + (size_t)NB_ * NV_;        // 32,768
  float* gd = gm + B_ * H_ * H_ * CI_;      // 32,768
  float* wt = gd + B_ * H_ * H_ * CI_;      // 36,864
  float* pt = wt + 36864;                   // 524,288 (pose transposed)

  transpose_all<<<2192, 256, 0, stream>>>(pose, pt, w, wt);
  caps_main<0><<<NB_, 256, 0, stream>>>(pt, act, wt, ba, bv, z, gm, gd, z, out);
  seg_reduce<<<512, 256, 0, stream>>>(z, gm, gd);
  caps_main<1><<<NB_, 256, 0, stream>>>(pt, act, wt, ba, bv, z, gm, gd, z, out);
  seg_reduce<<<512, 256, 0, stream>>>(z, gm, gd);
  caps_main<2><<<NB_, 256, 0, stream>>>(pt, act, wt, ba, bv, z, gm, gd, z, out);
}